// Round 1
// baseline (548.600 us; speedup 1.0000x reference)
//
#include <hip/hip_runtime.h>
#include <hip/hip_bf16.h>
#include <math.h>

#define NN 20000
#define NE 320000
#define IN_F 16
#define OUT_F 16
#define EHID 64
#define BN_EPS 1e-5f

// ws layout
#define NEIGH_BYTES (NN * OUT_F * 4)           // 1,280,000
#define BNACC_OFF   NEIGH_BYTES                // 32 floats
#define Y_OFF       (NEIGH_BYTES + 128)

// -------------------- edge path: one LANE per edge --------------------
// msg[e,o] = sum_i x[i] * ( be2[i*16+o] + sum_h eh[h]*We2[h*256+i*16+o] )
// eh[h] = relu(be1[h] + sum_i ef[i]*We1[i*64+h])
// All weight indices are wave-uniform -> scalar loads / SGPR operands.
__global__ __launch_bounds__(256) void edge_kernel(
    const float* __restrict__ h_neigh, const float* __restrict__ efeat,
    const int* __restrict__ src, const int* __restrict__ dst,
    const float* __restrict__ We1, const float* __restrict__ be1,
    const float* __restrict__ We2, const float* __restrict__ be2,
    float* __restrict__ neigh)
{
    int e = blockIdx.x * 256 + threadIdx.x;
    if (e >= NE) return;
    int s = src[e];
    int d = dst[e];

    float ef[16], x[16], msg[16];
    const float4* e4 = (const float4*)(efeat + (size_t)e * 16);
    const float4* x4 = (const float4*)(h_neigh + (size_t)s * 16);
#pragma unroll
    for (int k = 0; k < 4; k++) {
        float4 a = e4[k];
        ef[4*k+0] = a.x; ef[4*k+1] = a.y; ef[4*k+2] = a.z; ef[4*k+3] = a.w;
        float4 b = x4[k];
        x[4*k+0] = b.x; x[4*k+1] = b.y; x[4*k+2] = b.z; x[4*k+3] = b.w;
    }

#pragma unroll
    for (int o = 0; o < 16; o++) msg[o] = 0.f;

    // be2 contribution
#pragma unroll
    for (int i = 0; i < 16; i++) {
        float xi = x[i];
#pragma unroll
        for (int o = 0; o < 16; o++) msg[o] += xi * be2[i*16 + o];
    }

    for (int h = 0; h < EHID; h++) {
        float acc = be1[h];
#pragma unroll
        for (int i = 0; i < 16; i++) acc += ef[i] * We1[i*64 + h];
        acc = fmaxf(acc, 0.f);
        const float* w = We2 + (size_t)h * 256;
#pragma unroll
        for (int i = 0; i < 16; i++) {
            float exi = acc * x[i];
#pragma unroll
            for (int o = 0; o < 16; o++) msg[o] += exi * w[i*16 + o];
        }
    }

    float* np = neigh + (size_t)d * 16;
#pragma unroll
    for (int o = 0; o < 16; o++) atomicAdd(np + o, msg[o]);
}

// -------------------- self path: y = h_self @ W, BN stats --------------------
__global__ __launch_bounds__(256) void self_stats_kernel(
    const float* __restrict__ h_self, const float* __restrict__ W,
    float* __restrict__ y, float* __restrict__ bnacc)
{
    int n = blockIdx.x * 256 + threadIdx.x;
    bool act = (n < NN);
    float hv[16], yv[16];
    if (act) {
        const float4* h4 = (const float4*)(h_self + (size_t)n * 16);
#pragma unroll
        for (int k = 0; k < 4; k++) {
            float4 a = h4[k];
            hv[4*k+0] = a.x; hv[4*k+1] = a.y; hv[4*k+2] = a.z; hv[4*k+3] = a.w;
        }
    } else {
#pragma unroll
        for (int i = 0; i < 16; i++) hv[i] = 0.f;
    }
#pragma unroll
    for (int o = 0; o < 16; o++) {
        float a = 0.f;
#pragma unroll
        for (int i = 0; i < 16; i++) a += hv[i] * W[i*16 + o];
        yv[o] = a;
    }
    if (act) {
        float4* y4 = (float4*)(y + (size_t)n * 16);
#pragma unroll
        for (int k = 0; k < 4; k++)
            y4[k] = make_float4(yv[4*k+0], yv[4*k+1], yv[4*k+2], yv[4*k+3]);
    }
    int lane = threadIdx.x & 63;
#pragma unroll
    for (int o = 0; o < 16; o++) {
        float a = act ? yv[o] : 0.f;
        float b = act ? yv[o]*yv[o] : 0.f;
#pragma unroll
        for (int off = 32; off > 0; off >>= 1) {
            a += __shfl_down(a, off);
            b += __shfl_down(b, off);
        }
        if (lane == 0) {
            atomicAdd(&bnacc[o], a);
            atomicAdd(&bnacc[16 + o], b);
        }
    }
}

// -------------------- finalize: BN + tanh + add + relu + L2-normalize --------------------
__global__ __launch_bounds__(256) void final_kernel(
    const float* __restrict__ y, const float* __restrict__ neigh,
    const float* __restrict__ bnacc, const float* __restrict__ gamma,
    const float* __restrict__ beta, float* __restrict__ out)
{
    int n = blockIdx.x * 256 + threadIdx.x;
    if (n >= NN) return;
    float z[16];
    float ss = 0.f;
    const float inv_n = 1.f / (float)NN;
#pragma unroll
    for (int o = 0; o < 16; o++) {
        float mu  = bnacc[o] * inv_n;
        float var = bnacc[16 + o] * inv_n - mu * mu;
        float inv = rsqrtf(var + BN_EPS);
        float yv  = (y[(size_t)n*16 + o] - mu) * inv * gamma[o] + beta[o];
        float t   = tanhf(yv);
        float zz  = fmaxf(t + neigh[(size_t)n*16 + o], 0.f);
        z[o] = zz;
        ss += zz * zz;
    }
    float nrm = sqrtf(ss);
    if (nrm == 0.f) nrm = 1.f;
    float r = 1.f / nrm;
#pragma unroll
    for (int o = 0; o < 16; o++) out[(size_t)n*16 + o] = z[o] * r;
}

extern "C" void kernel_launch(void* const* d_in, const int* in_sizes, int n_in,
                              void* d_out, int out_size, void* d_ws, size_t ws_size,
                              hipStream_t stream) {
    const float* h_neigh = (const float*)d_in[0];
    const float* h_self  = (const float*)d_in[1];
    const float* efeat   = (const float*)d_in[2];
    const int*   src     = (const int*)d_in[3];
    const int*   dst     = (const int*)d_in[4];
    const float* W_self  = (const float*)d_in[5];
    const float* gamma   = (const float*)d_in[6];
    const float* beta    = (const float*)d_in[7];
    const float* We1     = (const float*)d_in[8];
    const float* be1     = (const float*)d_in[9];
    const float* We2     = (const float*)d_in[10];
    const float* be2     = (const float*)d_in[11];
    float* out = (float*)d_out;

    char* ws = (char*)d_ws;
    float* neigh = (float*)ws;
    float* bnacc = (float*)(ws + BNACC_OFF);
    float* y     = (float*)(ws + Y_OFF);

    // zero neigh accumulator + BN accumulators (ws is poisoned 0xAA each call)
    hipMemsetAsync(d_ws, 0, Y_OFF, stream);

    edge_kernel<<<(NE + 255)/256, 256, 0, stream>>>(
        h_neigh, efeat, src, dst, We1, be1, We2, be2, neigh);
    self_stats_kernel<<<(NN + 255)/256, 256, 0, stream>>>(h_self, W_self, y, bnacc);
    final_kernel<<<(NN + 255)/256, 256, 0, stream>>>(y, neigh, bnacc, gamma, beta, out);
}